// Round 10
// baseline (330.697 us; speedup 1.0000x reference)
//
#include <hip/hip_runtime.h>
#include <math.h>

#define TD 1024      // model dim
#define NH 16        // heads
#define HDIM 64      // head dim
#define SEQ 2048     // seq len
#define NB 2         // batch
#define NROWS 4096   // NB*SEQ
#define FFD 4096     // ffn dim

// 1/sqrt(64) * log2(e): softmax computed in exp2 domain; folded into Q at QKV epilogue
#define QSCALE 0.18033688011112042f

typedef unsigned short u16;
typedef __attribute__((ext_vector_type(8))) short bf16x8;   // 8 bf16 = 4 VGPR
typedef __attribute__((ext_vector_type(4))) float f32x4;    // MFMA acc

__device__ __forceinline__ u16 f2bf(float f) {
    union { float f; unsigned u; } v; v.f = f;
    return (u16)((v.u + 0x7FFFu + ((v.u >> 16) & 1u)) >> 16);
}

// async global->LDS, 16B per lane. LDS dest must be wave-uniform base + lane*16.
__device__ __forceinline__ void async16(void* lds, const void* g) {
    __builtin_amdgcn_global_load_lds(
        (const __attribute__((address_space(1))) unsigned*)g,
        (__attribute__((address_space(3))) unsigned*)lds, 16, 0, 0);
}

// tanh-form GELU (max |err| vs exact erf-GELU ~3e-3; threshold headroom 4x)
__device__ __forceinline__ float gelu_f(float v) {
    float u = 0.7978845608028654f * (v + 0.044715f * v * v * v);
    float e = __expf(2.f * u);
    float th = 1.f - 2.f * __builtin_amdgcn_rcpf(e + 1.f);
    return 0.5f * v * (1.f + th);
}

// ---------------- LayerNorm -> bf16 out: one block per row of 1024 -------------
__global__ __launch_bounds__(256) void ln_bf16(const float* __restrict__ x,
                                               const float* __restrict__ g,
                                               const float* __restrict__ b,
                                               u16* __restrict__ out)
{
    int row = blockIdx.x;
    const float* xr = x + (size_t)row * TD;
    u16* outr = out + (size_t)row * TD;
    int t = threadIdx.x;
    float v[4];
    float s = 0.f, ss = 0.f;
#pragma unroll
    for (int i = 0; i < 4; i++) {
        v[i] = xr[t + 256 * i];
        s += v[i];
        ss += v[i] * v[i];
    }
#pragma unroll
    for (int o = 32; o > 0; o >>= 1) {
        s  += __shfl_down(s, o);
        ss += __shfl_down(ss, o);
    }
    __shared__ float sm[4], sm2[4];
    int wave = t >> 6, lane = t & 63;
    if (lane == 0) { sm[wave] = s; sm2[wave] = ss; }
    __syncthreads();
    s  = sm[0] + sm[1] + sm[2] + sm[3];
    ss = sm2[0] + sm2[1] + sm2[2] + sm2[3];
    float mu  = s * (1.f / TD);
    float var = ss * (1.f / TD) - mu * mu;
    float rstd = rsqrtf(var + 1e-5f);
#pragma unroll
    for (int i = 0; i < 4; i++) {
        int c = t + 256 * i;
        outr[c] = f2bf((v[i] - mu) * rstd * g[c] + b[c]);
    }
}

// --- prep: fused weight convert+transpose (blocks 0..3071) + LN1 (3072..7167) --
__global__ __launch_bounds__(256) void prep_kernel(
    const float* __restrict__ Wqkv, const float* __restrict__ Wo,
    const float* __restrict__ W1,   const float* __restrict__ W2,
    u16* __restrict__ wqkvT, u16* __restrict__ woT,
    u16* __restrict__ w1T,   u16* __restrict__ w2T,
    const float* __restrict__ x, const float* __restrict__ g1,
    const float* __restrict__ b1, u16* __restrict__ hbuf)
{
    int blk = blockIdx.x;
    int t = threadIdx.x;
    if (blk >= 3072) {               // ---- LN1 path ----
        int row = blk - 3072;
        const float* xr = x + (size_t)row * TD;
        u16* outr = hbuf + (size_t)row * TD;
        float v[4];
        float s = 0.f, ss = 0.f;
#pragma unroll
        for (int i = 0; i < 4; i++) {
            v[i] = xr[t + 256 * i];
            s += v[i];
            ss += v[i] * v[i];
        }
#pragma unroll
        for (int o = 32; o > 0; o >>= 1) {
            s  += __shfl_down(s, o);
            ss += __shfl_down(ss, o);
        }
        __shared__ float sm[4], sm2[4];
        int wave = t >> 6, lane = t & 63;
        if (lane == 0) { sm[wave] = s; sm2[wave] = ss; }
        __syncthreads();
        s  = sm[0] + sm[1] + sm[2] + sm[3];
        ss = sm2[0] + sm2[1] + sm2[2] + sm2[3];
        float mu  = s * (1.f / TD);
        float var = ss * (1.f / TD) - mu * mu;
        float rstd = rsqrtf(var + 1e-5f);
#pragma unroll
        for (int i = 0; i < 4; i++) {
            int c = t + 256 * i;
            outr[c] = f2bf((v[i] - mu) * rstd * g1[c] + b1[c]);
        }
        return;
    }
    // ---- weight transpose path ----
    const float* W; u16* Wt; int K, N, local, nx;
    if (blk < 768)       { W = Wqkv; Wt = wqkvT; K = TD;  N = 3 * TD; local = blk;        nx = 48; }
    else if (blk < 1024) { W = Wo;   Wt = woT;   K = TD;  N = TD;     local = blk - 768;  nx = 16; }
    else if (blk < 2048) { W = W1;   Wt = w1T;   K = TD;  N = FFD;    local = blk - 1024; nx = 64; }
    else                 { W = W2;   Wt = w2T;   K = FFD; N = TD;     local = blk - 2048; nx = 16; }
    int n0 = (local % nx) * 64, k0 = (local / nx) * 64;
    __shared__ u16 tile[64][65];
    int c = t & 63, rq = t >> 6;
#pragma unroll
    for (int i = 0; i < 16; i++) {
        int r = rq * 16 + i;
        tile[r][c] = f2bf(W[(size_t)(k0 + r) * N + n0 + c]);
    }
    __syncthreads();
#pragma unroll
    for (int i = 0; i < 16; i++) {
        int r = rq * 16 + i;
        Wt[(size_t)(n0 + r) * K + k0 + c] = tile[c][r];
    }
}

// ---------------- bf16 MFMA GEMM: 128xTN tile, BK=64 k-slab, dbuf LDS ----------
// C[M,N] = A[M,K] @ Bt[N,K]^T + bias, with epilogues.
// Pipeline: one barrier per K-step; prefetch of slab k+1 issued right AFTER the
// barrier that publishes slab k -> vmcnt(0) drain at the next barrier waits on
// loads that had a full compute phase in flight.
// LDS swizzle (full 3-bit, 128B rows): 16B chunk g of row r stored at slot
// g ^ (r&7). Frag read k-half h: offset ((lq^(lr&7))*16) ^ (h*64) -> 64 lanes
// spread 8 lanes per granule = structural minimum, 0 conflicts.
// XCD swizzle: tiles remapped so all N-tiles of an M-row land on one XCD's L2.
#define EPI_QKV 0
#define EPI_F32RES 1
#define EPI_GELU 2

template<int EPI, int TN, int BK>
__global__ __launch_bounds__(256) void gemm_mfma(int M, int N, int K,
    const u16* __restrict__ A, const u16* __restrict__ Bt,
    const float* __restrict__ bias, const float* __restrict__ res,
    float* __restrict__ Cf, u16* __restrict__ Cb,
    u16* __restrict__ qb, u16* __restrict__ kb, u16* __restrict__ vb)
{
    constexpr int WN  = TN / 2;               // per-wave N extent (2 waves along N)
    constexpr int NJ  = WN / 16;              // B frags per wave
    constexpr int KH  = BK / 32;              // 32-elem k-halves per slab
    constexpr int CPR = BK / 8;               // 16B chunks per tile-row (8)
    constexpr int ACH = (128 * CPR) / 256;    // A chunks per thread
    constexpr int BCH = (TN  * CPR) / 256;    // B chunks per thread
    constexpr int ASZ = 128 * BK * 2;         // bytes per A buffer
    constexpr int BSZ = TN  * BK * 2;
    __shared__ __align__(16) char smem[2 * (ASZ + BSZ)];

    int t = threadIdx.x;
    int lane = t & 63, w = t >> 6;
    int wm = w >> 1, wn = w & 1;              // 2x2 wave grid: wave = 64(M) x WN(N)
    int lr = lane & 15, lq = lane >> 4;
    // XCD-aware tile remap (gridDim.y % 8 == 0 for all our launches)
    int gx = gridDim.x;
    int lin = blockIdx.x + gx * blockIdx.y;
    int li = lin >> 3;
    int qy = li / gx;
    int ty = (lin & 7) * (gridDim.y >> 3) + qy;
    int tx = li - qy * gx;
    int m0 = ty * 128, n0 = tx * TN;
    int pg = (lq ^ (lr & (CPR - 1))) * 16;    // swizzled frag-read granule offset

    // per-thread staging source pointers (bumped by BK each slab)
    const u16* ap[ACH];
    const u16* bp[BCH];
#pragma unroll
    for (int i = 0; i < ACH; i++) {
        int c = t + 256 * i, r = c / CPR, s = c % CPR;
        int g = s ^ (r & (CPR - 1));
        ap[i] = A + (size_t)(m0 + r) * K + g * 8;
    }
#pragma unroll
    for (int i = 0; i < BCH; i++) {
        int c = t + 256 * i, r = c / CPR, s = c % CPR;
        int g = s ^ (r & (CPR - 1));
        bp[i] = Bt + (size_t)(n0 + r) * K + g * 8;
    }

    f32x4 acc[4][NJ];
#pragma unroll
    for (int i = 0; i < 4; i++)
#pragma unroll
        for (int j = 0; j < NJ; j++) acc[i][j] = (f32x4){0.f, 0.f, 0.f, 0.f};

    // prologue: stage slab 0 into buffer 0
#pragma unroll
    for (int i = 0; i < ACH; i++)
        async16(smem + (t + 256 * i) * 16, ap[i]);
#pragma unroll
    for (int i = 0; i < BCH; i++)
        async16(smem + 2 * ASZ + (t + 256 * i) * 16, bp[i]);

    int nk = K / BK;
    for (int kt = 0; kt < nk; kt++) {
        int cur = kt & 1;
        __syncthreads();                      // slab kt ready; other buffer free
        if (kt + 1 < nk) {                    // prefetch slab kt+1 (drains at next barrier)
            char* An = smem + (1 - cur) * ASZ;
            char* Bn = smem + 2 * ASZ + (1 - cur) * BSZ;
#pragma unroll
            for (int i = 0; i < ACH; i++) {
                ap[i] += BK;
                async16(An + (t + 256 * i) * 16, ap[i]);
            }
#pragma unroll
            for (int i = 0; i < BCH; i++) {
                bp[i] += BK;
                async16(Bn + (t + 256 * i) * 16, bp[i]);
            }
        }
        const char* Ac = smem + cur * ASZ;
        const char* Bc = smem + 2 * ASZ + cur * BSZ;
#pragma unroll
        for (int h = 0; h < KH; h++) {
            bf16x8 af[4], bfr[NJ];
#pragma unroll
            for (int i = 0; i < 4; i++)
                af[i] = *(const bf16x8*)(Ac + (wm * 64 + i * 16 + lr) * (2 * BK) + (pg ^ (h * 64)));
#pragma unroll
            for (int j = 0; j < NJ; j++)
                bfr[j] = *(const bf16x8*)(Bc + (wn * WN + j * 16 + lr) * (2 * BK) + (pg ^ (h * 64)));
#pragma unroll
            for (int i = 0; i < 4; i++)
#pragma unroll
                for (int j = 0; j < NJ; j++)
                    acc[i][j] = __builtin_amdgcn_mfma_f32_16x16x32_bf16(af[i], bfr[j], acc[i][j], 0, 0, 0);
        }
    }

#pragma unroll
    for (int i = 0; i < 4; i++) {
        int rowb = m0 + wm * 64 + i * 16 + lq * 4;
#pragma unroll
        for (int j = 0; j < NJ; j++) {
            int col = n0 + wn * WN + j * 16 + lr;
            float bs = bias[col];
            float vals[4];
#pragma unroll
            for (int r = 0; r < 4; r++) vals[r] = acc[i][j][r] + bs;
            if (EPI == EPI_F32RES) {
#pragma unroll
                for (int r = 0; r < 4; r++) {
                    int rr = rowb + r;
                    Cf[(size_t)rr * N + col] = vals[r] + res[(size_t)rr * N + col];
                }
            } else if (EPI == EPI_GELU) {
#pragma unroll
                for (int r = 0; r < 4; r++)
                    Cb[(size_t)(rowb + r) * N + col] = f2bf(gelu_f(vals[r]));
            } else { // QKV scatter: Q/K [bh][seq][64] (Q pre-scaled), V [bh][64][seq]
                int comp = col >> 10, cw = col & 1023;
                int h = cw >> 6, d = cw & 63;
                int bb0 = rowb >> 11, ts = rowb & 2047;   // rowb%4==0: no batch crossing
                int bh = bb0 * NH + h;
                if (comp == 0) {
#pragma unroll
                    for (int r = 0; r < 4; r++)
                        qb[((size_t)bh * SEQ + ts + r) * HDIM + d] = f2bf(vals[r] * QSCALE);
                } else if (comp == 1) {
#pragma unroll
                    for (int r = 0; r < 4; r++)
                        kb[((size_t)bh * SEQ + ts + r) * HDIM + d] = f2bf(vals[r]);
                } else {
                    ushort4 pk;
                    pk.x = f2bf(vals[0]); pk.y = f2bf(vals[1]);
                    pk.z = f2bf(vals[2]); pk.w = f2bf(vals[3]);
                    *(ushort4*)&vb[((size_t)bh * HDIM + d) * SEQ + ts] = pk;
                }
            }
        }
    }
}

// ---------------- flash attention v4: 1 q-tile/block, 4 blocks/CU --------------
// qb/kb: [bh][seq][64] bf16 (q pre-scaled by QSCALE); vb: [bh][64][seq] bf16
// Grid 1024 = 32 bh x 32 q-tiles. Remap: bh = xcd + 8*j keeps 4 heads per XCD
// (K/V L2-resident); qt chosen so any 4 consecutive XCD-local blocks have
// iteration counts summing to ~62 (balanced under blocked dispatch), and
// round-robin windows stay within ~20%.
// LDS 40KB -> 4 blocks/CU co-resident = 4 waves/SIMD of latency hiding.
// All tiles XOR-swizzled: chunk g of row r at byte r*128 + ((g^(r&7))*16).
__global__ __launch_bounds__(256, 4) void attn_mfma(const u16* __restrict__ qb,
                                                    const u16* __restrict__ kb,
                                                    const u16* __restrict__ vb,
                                                    u16* __restrict__ ctx)
{
    __shared__ __align__(16) char smem[40960];
    char* QP = smem;                        // 8KB Q tile / P buffer (wave-private rows)
    int lin = blockIdx.x;
    int xcd = lin & 7, idx = lin >> 3;      // idx 0..127 within XCD cluster
    int j4 = idx & 3, q4 = idx >> 2;        // j4: head slot, q4: 0..31
    int bh = xcd + 8 * j4;
    int qx = (q4 + 8 * j4) & 31;
    int qt = (j4 & 1) ? (31 - qx) : qx;     // balanced q-tile assignment
    int bb = bh >> 4, h = bh & 15;
    int t = threadIdx.x, lane = t & 63, w = t >> 6;
    int lr = lane & 15, lq = lane >> 4;
    int sw = (lr & 7) * 16;                 // read-side swizzle
    int cA = (lq * 16) ^ sw;                // chunk lq   (k-half 0)
    int cB = (64 | (lq * 16)) ^ sw;         // chunk 4+lq (k-half 1)
    // staging: thread covers LDS chunks t and t+256; swizzled global source
    int c0 = t,        r0 = c0 >> 3, g0 = (c0 & 7) ^ (r0 & 7);
    int c1 = t + 256,  r1 = c1 >> 3, g1 = (c1 & 7) ^ (r1 & 7);
    size_t off0  = (size_t)r0 * 128  + g0 * 16;   // Q/K tiles: 128B per row
    size_t off1  = (size_t)r1 * 128  + g1 * 16;
    size_t voff0 = (size_t)r0 * 4096 + g0 * 16;   // V: row=d, global stride 4096B
    size_t voff1 = (size_t)r1 * 4096 + g1 * 16;

    const char* qg_base = (const char*)qb + (size_t)bh * SEQ * 128;
    const char* kg_base = (const char*)kb + (size_t)bh * SEQ * 128;
    const char* vg_base = (const char*)vb + (size_t)bh * 64 * 4096;

    const char* qg = qg_base + (size_t)qt * 8192;
    async16(QP + c0 * 16, qg + off0);
    async16(QP + c1 * 16, qg + off1);
    async16(smem + 8192 + c0 * 16, kg_base + off0);
    async16(smem + 8192 + c1 * 16, kg_base + off1);
    async16(smem + 24576 + c0 * 16, vg_base + voff0);
    async16(smem + 24576 + c1 * 16, vg_base + voff1);

    float mold = -INFINITY, lsum = 0.f;
    f32x4 o[4];
#pragma unroll
    for (int dj = 0; dj < 4; dj++) o[dj] = (f32x4){0.f, 0.f, 0.f, 0.f};
    bf16x8 bq0, bq1;

    for (int kt = 0; kt <= qt; ++kt) {
        int cur = kt & 1;
        __syncthreads();                // tile kt ready; other buf free
        if (kt < qt) {                  // prefetch kt+1 (drained at next barrier)
            const char* kgn = kg_base + (size_t)(kt + 1) * 8192;
            const char* vgn = vg_base + (size_t)(kt + 1) * 128;
            char* Kn = smem + 8192  + (1 - cur) * 8192;
            char* Vn = smem + 24576 + (1 - cur) * 8192;
            async16(Kn + c0 * 16, kgn + off0);
            async16(Kn + c1 * 16, kgn + off1);
            async16(Vn + c0 * 16, vgn + voff0);
            async16(Vn + c1 * 16, vgn + voff1);
        }
        if (kt == 0) {                  // Q frags -> regs (QP then reused as P)
            const char* qr = QP + (w * 16 + lr) * 128;
            bq0 = *(const bf16x8*)(qr + cA);
            bq1 = *(const bf16x8*)(qr + cB);
        }
        const char* Kc = smem + 8192  + cur * 8192;
        const char* Vc = smem + 24576 + cur * 8192;

        // S^T = K Q^T : lane holds keys j*16+lq*4+r (rows), q = w*16+lr (col)
        float sv[4][4];
        bool diag = (kt == qt);
#pragma unroll
        for (int j = 0; j < 4; ++j) {
            const char* kr = Kc + (j * 16 + lr) * 128;
            bf16x8 ak0 = *(const bf16x8*)(kr + cA);
            bf16x8 ak1 = *(const bf16x8*)(kr + cB);
            f32x4 z = (f32x4){0.f, 0.f, 0.f, 0.f};
            z = __builtin_amdgcn_mfma_f32_16x16x32_bf16(ak0, bq0, z, 0, 0, 0);
            z = __builtin_amdgcn_mfma_f32_16x16x32_bf16(ak1, bq1, z, 0, 0, 0);
#pragma unroll
            for (int r = 0; r < 4; r++) {
                float xv = z[r];
                if (diag && (j * 16 + lq * 4 + r > w * 16 + lr)) xv = -INFINITY;
                sv[j][r] = xv;
            }
        }
        // online softmax in exp2 domain; one q per lane
        float mx = sv[0][0];
#pragma unroll
        for (int j = 0; j < 4; j++)
#pragma unroll
            for (int r = 0; r < 4; r++) mx = fmaxf(mx, sv[j][r]);
        mx = fmaxf(mx, __shfl_xor(mx, 16));
        mx = fmaxf(mx, __shfl_xor(mx, 32));
        float mnew = fmaxf(mold, mx);
        float alpha = exp2f(mold - mnew);
        float rs = 0.f;
        unsigned pk[4][2];
#pragma unroll
        for (int j = 0; j < 4; j++)
#pragma unroll
            for (int hh = 0; hh < 2; hh++) {
                float p0 = exp2f(sv[j][2 * hh]     - mnew);
                float p1 = exp2f(sv[j][2 * hh + 1] - mnew);
                rs += p0 + p1;
                union { float f; unsigned u; } a0, a1;
                a0.f = p0; a1.f = p1;
                // truncation-pack: D = {hi16(p1), hi16(p0)} in ONE v_perm_b32
                pk[j][hh] = __builtin_amdgcn_perm(a1.u, a0.u, 0x07060302u);
            }
        rs += __shfl_xor(rs, 16);
        rs += __shfl_xor(rs, 32);
        lsum = lsum * alpha + rs;
        mold = mnew;
#pragma unroll
        for (int dj = 0; dj < 4; dj++)
#pragma unroll
            for (int r = 0; r < 4; r++) o[dj][r] *= alpha;

        // P^T -> LDS (wave-private rows; no barrier): row q=w*16+lr, b64 writes
        {
            char* pw = QP + (w * 16 + lr) * 128 + (lq & 1) * 8;
#pragma unroll
            for (int j = 0; j < 4; j++) {
                int pos = ((j * 2 + (lq >> 1)) * 16) ^ sw;
                uint2 u; u.x = pk[j][0]; u.y = pk[j][1];
                *(uint2*)(pw + pos) = u;
            }
        }
        asm volatile("s_waitcnt lgkmcnt(0)" ::: "memory");
        const char* pr = QP + (w * 16 + lr) * 128;
        bf16x8 bp0 = *(const bf16x8*)(pr + cA);
        bf16x8 bp1 = *(const bf16x8*)(pr + cB);
        // O^T += V^T P^T : rows d, cols q
#pragma unroll
        for (int dj = 0; dj < 4; ++dj) {
            const char* vr = Vc + (dj * 16 + lr) * 128;
            bf16x8 av0 = *(const bf16x8*)(vr + cA);
            bf16x8 av1 = *(const bf16x8*)(vr + cB);
            o[dj] = __builtin_amdgcn_mfma_f32_16x16x32_bf16(av0, bp0, o[dj], 0, 0, 0);
            o[dj] = __builtin_amdgcn_mfma_f32_16x16x32_bf16(av1, bp1, o[dj], 0, 0, 0);
        }
    }

    float inv = 1.f / lsum;
    int tok = qt * 64 + w * 16 + lr;
    u16* cp = ctx + ((size_t)(bb * SEQ) + tok) * TD + h * HDIM + lq * 4;
#pragma unroll
    for (int dj = 0; dj < 4; dj++) {
        ushort4 s4;
        s4.x = f2bf(o[dj][0] * inv); s4.y = f2bf(o[dj][1] * inv);
        s4.z = f2bf(o[dj][2] * inv); s4.w = f2bf(o[dj][3] * inv);
        *(ushort4*)(cp + dj * 16) = s4;
    }
}

extern "C" void kernel_launch(void* const* d_in, const int* in_sizes, int n_in,
                              void* d_out, int out_size, void* d_ws, size_t ws_size,
                              hipStream_t stream)
{
    const float* x    = (const float*)d_in[0];
    const float* g1   = (const float*)d_in[1];
    const float* b1   = (const float*)d_in[2];
    const float* Wqkv = (const float*)d_in[3];
    const float* bqkv = (const float*)d_in[4];
    const float* Wo   = (const float*)d_in[5];
    const float* bo   = (const float*)d_in[6];
    const float* g2   = (const float*)d_in[7];
    const float* b2   = (const float*)d_in[8];
    const float* W1   = (const float*)d_in[9];
    const float* b1f  = (const float*)d_in[10];
    const float* W2   = (const float*)d_in[11];
    const float* b2f  = (const float*)d_in[12];
    float* out = (float*)d_out;

    char* ws = (char*)d_ws;
    const size_t MB = 1ull << 20;
    u16* wqkvT = (u16*)(ws + 0 * MB);    // 6 MB  [3072][1024]
    u16* woT   = (u16*)(ws + 6 * MB);    // 2 MB  [1024][1024]
    u16* w1T   = (u16*)(ws + 8 * MB);    // 8 MB  [4096][1024]
    u16* w2T   = (u16*)(ws + 16 * MB);   // 8 MB  [1024][4096]
    u16* qbuf  = (u16*)(ws + 24 * MB);   // 8 MB  [32][2048][64] (pre-scaled)
    u16* kbuf  = (u16*)(ws + 32 * MB);   // 8 MB
    u16* vbuf  = (u16*)(ws + 40 * MB);   // 8 MB  [32][64][2048]
    u16* hbuf  = (u16*)(ws + 48 * MB);   // 8 MB  h then hh
    u16* ctx   = (u16*)(ws + 56 * MB);   // 8 MB
    float* x2  = (float*)(ws + 64 * MB); // 16 MB
    u16* ff1   = (u16*)(ws + 80 * MB);   // 32 MB  -> 112 MB total

    // fused: weight transposes + LN1 (independent work, one dispatch)
    prep_kernel<<<3072 + NROWS, 256, 0, stream>>>(
        Wqkv, Wo, W1, W2, wqkvT, woT, w1T, w2T, x, g1, b1, hbuf);

    gemm_mfma<EPI_QKV, 128, 64><<<dim3(3 * TD / 128, NROWS / 128), 256, 0, stream>>>(
        NROWS, 3 * TD, TD, hbuf, wqkvT, bqkv, nullptr, nullptr, nullptr, qbuf, kbuf, vbuf);
    attn_mfma<<<1024, 256, 0, stream>>>(qbuf, kbuf, vbuf, ctx);
    gemm_mfma<EPI_F32RES, 64, 64><<<dim3(TD / 64, NROWS / 128), 256, 0, stream>>>(
        NROWS, TD, TD, ctx, woT, bo, x, x2, nullptr, nullptr, nullptr, nullptr);
    ln_bf16<<<NROWS, 256, 0, stream>>>(x2, g2, b2, hbuf);
    gemm_mfma<EPI_GELU, 128, 64><<<dim3(FFD / 128, NROWS / 128), 256, 0, stream>>>(
        NROWS, FFD, TD, hbuf, w1T, b1f, nullptr, nullptr, ff1, nullptr, nullptr, nullptr);
    gemm_mfma<EPI_F32RES, 64, 64><<<dim3(TD / 64, NROWS / 128), 256, 0, stream>>>(
        NROWS, TD, FFD, ff1, w2T, b2f, x2, out, nullptr, nullptr, nullptr, nullptr);
}